// Round 4
// baseline (883.832 us; speedup 1.0000x reference)
//
#include <hip/hip_runtime.h>
#include <math.h>

#define CCH   50
#define HH    256
#define WW    256
#define BATCH 16
#define HSZ   64
#define WSZ   64
#define NTOP  240
#define COC   10          // output channels per pass
#define NPASS 5

#define REPEAT10(M) M(0) M(1) M(2) M(3) M(4) M(5) M(6) M(7) M(8) M(9)

// ---------------- Kernel 1: conv3x3 (50->50) + ReLU ----------------
// 5 serial passes of 10 output channels: 20 named accumulators fit arch
// VGPRs (no AGPR shuffle), 24 KB LDS weight stage per pass (broadcast
// ds_read_b128), 4 blocks/CU. Block = 512 thr = 256 cols x 2 row-pairs.
__global__ __launch_bounds__(512, 8) void conv1_relu_k(
    const float* __restrict__ in, const float* __restrict__ w1,
    const float* __restrict__ b1, float* __restrict__ x1) {
  __shared__ float wlds[COC * CCH * 12];        // [co][ci][12] (9 used), 24 KB

  int bx = blockIdx.x;
  int b  = bx >> 6;                 // batch
  int rg = bx & 63;                 // row group (4 rows each)
  int t  = threadIdx.x;
  int w  = t & 255;
  int rp = t >> 8;                  // 0/1: row pair within group
  int h0 = rg * 4 + rp * 2;

  const float* ip = in + ((size_t)b * CCH << 16) + h0 * WW + w;

  bool hm = h0 > 0;
  bool hp = h0 < HH - 2;
  bool wm = w > 0, wp = w < WW - 1;

  for (int pass = 0; pass < NPASS; ++pass) {
    int cbase = pass * COC;
    __syncthreads();                // prev-pass LDS reads complete
    for (int e = t; e < COC * CCH * 9; e += 512) {
      int co = e / (CCH * 9);
      int rem = e - co * (CCH * 9);
      int ci = rem / 9;
      int k  = rem - ci * 9;
      wlds[(co * CCH + ci) * 12 + k] = w1[(cbase + co) * (CCH * 9) + ci * 9 + k];
    }
    __syncthreads();

#define DECL(i) float A##i = b1[cbase + (i)]; float B##i = A##i;
    REPEAT10(DECL)
#undef DECL

    for (int ci = 0; ci < CCH; ++ci) {
      const float* p = ip + ((size_t)ci << 16);
      float a0 = (hm && wm) ? p[-257] : 0.f;
      float a1 = hm         ? p[-256] : 0.f;
      float a2 = (hm && wp) ? p[-255] : 0.f;
      float r0 = wm         ? p[-1]   : 0.f;
      float r1 =              p[0];
      float r2 = wp         ? p[1]    : 0.f;
      float c0 = wm         ? p[255]  : 0.f;
      float c1 =              p[256];
      float c2 = wp         ? p[257]  : 0.f;
      float d0 = (hp && wm) ? p[511]  : 0.f;
      float d1 = hp         ? p[512]  : 0.f;
      float d2 = (hp && wp) ? p[513]  : 0.f;
      const float* wl = &wlds[ci * 12];         // + i*600 per STEP (imm offsets)
#define STEP(i) { \
    const float4 wA = *(const float4*)&wl[(i) * (CCH * 12)]; \
    const float4 wB = *(const float4*)&wl[(i) * (CCH * 12) + 4]; \
    const float  w8 = wl[(i) * (CCH * 12) + 8]; \
    A##i = fmaf(wA.x, a0, A##i); A##i = fmaf(wA.y, a1, A##i); A##i = fmaf(wA.z, a2, A##i); \
    A##i = fmaf(wA.w, r0, A##i); A##i = fmaf(wB.x, r1, A##i); A##i = fmaf(wB.y, r2, A##i); \
    A##i = fmaf(wB.z, c0, A##i); A##i = fmaf(wB.w, c1, A##i); A##i = fmaf(w8,  c2, A##i); \
    B##i = fmaf(wA.x, r0, B##i); B##i = fmaf(wA.y, r1, B##i); B##i = fmaf(wA.z, r2, B##i); \
    B##i = fmaf(wA.w, c0, B##i); B##i = fmaf(wB.x, c1, B##i); B##i = fmaf(wB.y, c2, B##i); \
    B##i = fmaf(wB.z, d0, B##i); B##i = fmaf(wB.w, d1, B##i); B##i = fmaf(w8,  d2, B##i); }
      REPEAT10(STEP)
#undef STEP
    }

    float* op = x1 + (((size_t)b * CCH + cbase) << 16) + h0 * WW + w;
#define STORE(i) { float* o = op + ((size_t)(i) << 16); \
    o[0]  = fmaxf(A##i, 0.f); o[WW] = fmaxf(B##i, 0.f); }
    REPEAT10(STORE)
#undef STORE
  }
}

// ---------------- Kernel 2: conv3x3 (50->2) + softmax[:,1] ----------------
__global__ __launch_bounds__(256) void conv2_softmax_k(
    const float* __restrict__ x1, const float* __restrict__ w2,
    const float* __restrict__ b2, float* __restrict__ sm) {
  int idx = blockIdx.x * 256 + threadIdx.x;
  int b = idx >> 16, hw = idx & 65535;
  int h = hw >> 8, w = hw & 255;
  const float* ip = x1 + (size_t)b * CCH * 65536 + hw;

  float a0 = b2[0], a1 = b2[1];
  bool hm = h > 0, hp = h < HH - 1, wm = w > 0, wp = w < WW - 1;

  for (int ci = 0; ci < CCH; ++ci) {
    const float* p = ip + (size_t)ci * 65536;
    float v0 = (hm && wm) ? p[-257] : 0.f;
    float v1 = hm         ? p[-256] : 0.f;
    float v2 = (hm && wp) ? p[-255] : 0.f;
    float v3 = wm         ? p[-1]   : 0.f;
    float v4 =              p[0];
    float v5 = wp         ? p[1]    : 0.f;
    float v6 = (hp && wm) ? p[255]  : 0.f;
    float v7 = hp         ? p[256]  : 0.f;
    float v8 = (hp && wp) ? p[257]  : 0.f;
    const float* q0 = w2 + ci * 9;
    const float* q1 = w2 + CCH * 9 + ci * 9;
    a0 = fmaf(q0[0], v0, a0); a0 = fmaf(q0[1], v1, a0); a0 = fmaf(q0[2], v2, a0);
    a0 = fmaf(q0[3], v3, a0); a0 = fmaf(q0[4], v4, a0); a0 = fmaf(q0[5], v5, a0);
    a0 = fmaf(q0[6], v6, a0); a0 = fmaf(q0[7], v7, a0); a0 = fmaf(q0[8], v8, a0);
    a1 = fmaf(q1[0], v0, a1); a1 = fmaf(q1[1], v1, a1); a1 = fmaf(q1[2], v2, a1);
    a1 = fmaf(q1[3], v3, a1); a1 = fmaf(q1[4], v4, a1); a1 = fmaf(q1[5], v5, a1);
    a1 = fmaf(q1[6], v6, a1); a1 = fmaf(q1[7], v7, a1); a1 = fmaf(q1[8], v8, a1);
  }
  sm[(size_t)b * 65536 + hw] = 1.f / (1.f + expf(a0 - a1));
}

// ---------------- Kernel 3: 4x4 avg pool + LeakyReLU(0.1) ----------------
__global__ __launch_bounds__(256) void pool_leaky_k(
    const float* __restrict__ sm, float* __restrict__ pool) {
  int idx = blockIdx.x * 256 + threadIdx.x;      // b*4096 + hs*64 + ws
  int b = idx >> 12, hw = idx & 4095;
  int hs = hw >> 6, ws = hw & 63;
  const float* p = sm + (size_t)b * 65536 + hs * 4 * WW + ws * 4;
  float s = 0.f;
#pragma unroll
  for (int r = 0; r < 4; ++r)
#pragma unroll
    for (int c = 0; c < 4; ++c) s += p[r * WW + c];
  s *= (1.f / 16.f);
  pool[idx] = (s >= 0.f) ? s : 0.1f * s;
}

// ---------------- Kernel 4: 25-tap learned mixing -> final_mask ----------------
__global__ __launch_bounds__(256) void mix_mask_k(
    const float* __restrict__ pool, const float* __restrict__ wk,
    const float* __restrict__ bk, float* __restrict__ mask_out) {
  int idx = blockIdx.x * 256 + threadIdx.x;      // b*4096 + hs*64 + ws
  int b = idx >> 12, hw = idx & 4095;
  int hs = hw >> 6, ws = hw & 63;
  float c = pool[idx];
  float s = 0.f;
#pragma unroll
  for (int i = 0; i < 5; ++i) {
#pragma unroll
    for (int j = 0; j < 5; ++j) {
      int y = hs + i - 2, x = ws + j - 2;
      float win = (y >= 0 && y < HSZ && x >= 0 && x < WSZ)
                      ? pool[(size_t)b * 4096 + y * WSZ + x] : 0.f;
      int k = i * 5 + j;
      s += (wk[k] * c + bk[k]) * win;
    }
  }
  mask_out[idx] = s;
}

// ---------------- Kernel 5: per-batch top-240 + ascending index sort ----------------
__global__ __launch_bounds__(256) void topk_sort_k(
    const float* __restrict__ mask, float* __restrict__ ob, float* __restrict__ oh,
    float* __restrict__ ow, int* __restrict__ idx_ws) {
  __shared__ unsigned long long keys[4096];
  __shared__ int sidx[256];
  int b = blockIdx.x, t = threadIdx.x;

  for (int i = t; i < 4096; i += 256) {
    float v = mask[(size_t)b * 4096 + i];
    unsigned u = __float_as_uint(v);
    u = (u & 0x80000000u) ? ~u : (u | 0x80000000u);   // order-preserving map
    u = ~u;                                            // ascending sort -> value desc
    keys[i] = ((unsigned long long)u << 12) | (unsigned)i;  // tie: lower idx first
  }
  __syncthreads();

  for (int k = 2; k <= 4096; k <<= 1) {
    for (int j = k >> 1; j > 0; j >>= 1) {
      for (int m = t; m < 2048; m += 256) {
        int i = ((m & ~(j - 1)) << 1) | (m & (j - 1));
        int l = i | j;
        bool up = ((i & k) == 0);
        unsigned long long a = keys[i], c = keys[l];
        if ((a > c) == up) { keys[i] = c; keys[l] = a; }
      }
      __syncthreads();
    }
  }

  sidx[t] = (t < NTOP) ? (int)(keys[t] & 0xFFFu) : 0x7FFFFFFF;
  __syncthreads();
  for (int k = 2; k <= 256; k <<= 1) {
    for (int j = k >> 1; j > 0; j >>= 1) {
      if (t < 128) {
        int i = ((t & ~(j - 1)) << 1) | (t & (j - 1));
        int l = i | j;
        bool up = ((i & k) == 0);
        int a = sidx[i], c = sidx[l];
        if ((a > c) == up) { sidx[i] = c; sidx[l] = a; }
      }
      __syncthreads();
    }
  }

  if (t < NTOP) {
    int id = sidx[t];
    int o = b * NTOP + t;
    ob[o] = (float)b;
    oh[o] = (float)(id >> 6);
    ow[o] = (float)(id & 63);
    idx_ws[o] = id;
  }
}

// ---------------- Kernel 6: gather 6x6 patches (pad=1, stride=4) ----------------
__global__ __launch_bounds__(256) void gather_patch_k(
    const float* __restrict__ in, const int* __restrict__ idx_ws,
    float* __restrict__ patches) {
  int p = blockIdx.x;                 // 0 .. B*240-1
  int b = p / NTOP;
  int id = idx_ws[p];
  int h = id >> 6, w = id & 63;
  int y0 = h * 4 - 1, x0 = w * 4 - 1;
  const float* base = in + (size_t)b * CCH * 65536;
  float* op = patches + (size_t)p * (CCH * 36);
  for (int e = threadIdx.x; e < CCH * 36; e += 256) {
    int c = e / 36;
    int r = (e - c * 36) / 6;
    int col = e - c * 36 - r * 6;
    int y = y0 + r, x = x0 + col;
    float v = 0.f;
    if (y >= 0 && y < HH && x >= 0 && x < WW)
      v = base[(size_t)c * 65536 + y * WW + x];
    op[e] = v;
  }
}

extern "C" void kernel_launch(void* const* d_in, const int* in_sizes, int n_in,
                              void* d_out, int out_size, void* d_ws, size_t ws_size,
                              hipStream_t stream) {
  const float* out_lr = (const float*)d_in[0];
  const float* W1 = (const float*)d_in[1];
  const float* b1 = (const float*)d_in[2];
  const float* W2 = (const float*)d_in[3];
  const float* b2 = (const float*)d_in[4];
  const float* Wk = (const float*)d_in[5];
  const float* bk = (const float*)d_in[6];

  float* x1   = (float*)d_ws;                 // 16*50*256*256
  float* sm   = x1 + (size_t)52428800;        // 16*256*256
  float* pool = sm + (size_t)1048576;         // 16*64*64
  int*  idxb  = (int*)(pool + 65536);         // 16*240

  float* out    = (float*)d_out;
  float* o_patch = out;                        // 3840*50*36
  float* o_b    = out + (size_t)6912000;
  float* o_h    = o_b + 3840;
  float* o_w    = o_h + 3840;
  float* o_mask = o_w + 3840;                  // 16*4096

  conv1_relu_k<<<BATCH * 64, 512, 0, stream>>>(out_lr, W1, b1, x1);
  conv2_softmax_k<<<4096, 256, 0, stream>>>(x1, W2, b2, sm);
  pool_leaky_k<<<256, 256, 0, stream>>>(sm, pool);
  mix_mask_k<<<256, 256, 0, stream>>>(pool, Wk, bk, o_mask);
  topk_sort_k<<<BATCH, 256, 0, stream>>>(o_mask, o_b, o_h, o_w, idxb);
  gather_patch_k<<<BATCH * NTOP, 256, 0, stream>>>(out_lr, idxb, o_patch);
}

// Round 5
// 636.774 us; speedup vs baseline: 1.3880x; 1.3880x over previous
//
#include <hip/hip_runtime.h>
#include <math.h>

#define CCH   50
#define HH    256
#define WW    256
#define BATCH 16
#define HSZ   64
#define WSZ   64
#define NTOP  240

typedef __attribute__((ext_vector_type(8))) short s16x8;
typedef __attribute__((ext_vector_type(4))) float f32x4;

__device__ __forceinline__ unsigned short bf16rne(float x) {
  unsigned u = __float_as_uint(x);
  unsigned r = (u + 0x7FFFu + ((u >> 16) & 1u)) >> 16;
  return (unsigned short)r;
}
__device__ __forceinline__ float bf2f(unsigned short h) {
  return __uint_as_float(((unsigned)h) << 16);
}

// ---------------- Kernel 0: pack W1 into MFMA A-fragments (split bf16) ----
// wf layout: combo = ((chunk*9 + tap)*4 + mt)*2 + sp ; per combo 64 lanes x 8 bf16.
// element (lane, e): co = mt*16 + (lane&15), ci = chunk*32 + (lane>>4)*8 + e.
__global__ __launch_bounds__(64) void prep_wfrag_k(
    const float* __restrict__ W1, unsigned short* __restrict__ wf) {
  int combo = blockIdx.x;            // 0..143
  int lane = threadIdx.x;
  int sp = combo & 1;
  int t2 = combo >> 1;
  int mt = t2 & 3;
  int t3 = t2 >> 2;                  // 0..17
  int tap = t3 % 9;
  int chunk = t3 / 9;
  int co = mt * 16 + (lane & 15);
  int gbase = combo * 512 + lane * 8;
#pragma unroll
  for (int e = 0; e < 8; ++e) {
    int ci = chunk * 32 + ((lane >> 4) * 8) + e;
    float w = (co < CCH && ci < CCH) ? W1[co * (CCH * 9) + ci * 9 + tap] : 0.f;
    unsigned short h = bf16rne(w);
    unsigned short v = sp ? bf16rne(w - bf2f(h)) : h;
    wf[gbase + e] = v;
  }
}

// ---------------- Kernel 1: conv3x3 (50->50) + ReLU via MFMA -------------
// Implicit GEMM: per tap (dh,dw), Y[co,pix] += W[co,ci,tap] * X[ci, pix+d].
// Split bf16 (hi+lo) on both operands, 3 products -> ~2^-16 rel precision.
// Block 256 thr = 4 waves; tile 64co x 2rows x 64px; LDS = one 32-ci chunk.
__global__ __launch_bounds__(256, 4) void conv1_mfma_k(
    const float* __restrict__ in, const unsigned short* __restrict__ wf,
    const float* __restrict__ b1, float* __restrict__ x1) {
  // LDS: [row 0..3][px 0..65][hi: ci 0..31 | lo: ci 0..31 | pad 4]
  __shared__ alignas(16) short xlds[4 * 66 * 72];   // 38016 B

  int bx = blockIdx.x;
  int pq = bx & 3;                   // px quarter
  int rp = (bx >> 2) & 127;          // row pair
  int b  = bx >> 9;                  // batch
  int row0 = rp * 2;
  int px0g = pq * 64;

  int t = threadIdx.x;
  int lane = t & 63;
  int wv = t >> 6;
  int ch = wv & 1;                   // co half: 0 -> co 0..31, 1 -> 32..63
  int ph = wv >> 1;                  // px half within 64: 0 or 32
  int ln15 = lane & 15;
  int lg = lane >> 4;

  f32x4 acc[2][2][2];                // [mt][r][s]
#pragma unroll
  for (int mt = 0; mt < 2; ++mt)
#pragma unroll
    for (int r = 0; r < 2; ++r)
#pragma unroll
      for (int s = 0; s < 2; ++s) acc[mt][r][s] = (f32x4){0.f, 0.f, 0.f, 0.f};

  const size_t in_b = ((size_t)b * CCH) << 16;

  for (int chunk = 0; chunk < 2; ++chunk) {
    __syncthreads();                 // previous chunk's reads done
    // ---- stage 32 ci x 4 rows x 66 px, split to bf16 hi/lo ----
    for (int i = t; i < 8448; i += 256) {        // 32*264 ; 33 iters exactly
      int ci_l = i / 264;
      int rem = i - ci_l * 264;
      int row = rem / 66;
      int px = rem - row * 66;
      int gr = row0 - 1 + row;
      int gx = px0g - 1 + px;
      int ci = chunk * 32 + ci_l;
      float x = 0.f;
      if (ci < CCH && gr >= 0 && gr < HH && gx >= 0 && gx < WW)
        x = in[in_b + ((size_t)ci << 16) + (gr << 8) + gx];
      unsigned short h = bf16rne(x);
      unsigned short l = bf16rne(x - bf2f(h));
      int base = row * 4752 + px * 72;
      xlds[base + ci_l] = (short)h;
      xlds[base + 32 + ci_l] = (short)l;
    }
    __syncthreads();

    // ---- 9 taps ----
#pragma unroll
    for (int tap = 0; tap < 9; ++tap) {
      const int dh = tap / 3 - 1;
      const int dw = tap % 3 - 1;
      // B fragments: [r][s] hi & lo
      s16x8 bh[2][2], bl[2][2];
#pragma unroll
      for (int r = 0; r < 2; ++r)
#pragma unroll
        for (int s = 0; s < 2; ++s) {
          int pixL = 1 + ph * 32 + s * 16 + ln15 + dw;
          int addr = (r + 1 + dh) * 4752 + pixL * 72 + lg * 8;
          bh[r][s] = *(const s16x8*)&xlds[addr];
          bl[r][s] = *(const s16x8*)&xlds[addr + 32];
        }
      // A fragments + MFMA
#pragma unroll
      for (int mt = 0; mt < 2; ++mt) {
        int mtg = ch * 2 + mt;
        int cbase = ((chunk * 9 + tap) * 4 + mtg) * 2;
        const s16x8 ah = *(const s16x8*)(wf + (size_t)(cbase + 0) * 512 + lane * 8);
        const s16x8 al = *(const s16x8*)(wf + (size_t)(cbase + 1) * 512 + lane * 8);
#pragma unroll
        for (int r = 0; r < 2; ++r)
#pragma unroll
          for (int s = 0; s < 2; ++s) {
            acc[mt][r][s] = __builtin_amdgcn_mfma_f32_16x16x32_bf16(
                ah, bh[r][s], acc[mt][r][s], 0, 0, 0);
            acc[mt][r][s] = __builtin_amdgcn_mfma_f32_16x16x32_bf16(
                ah, bl[r][s], acc[mt][r][s], 0, 0, 0);
            acc[mt][r][s] = __builtin_amdgcn_mfma_f32_16x16x32_bf16(
                al, bh[r][s], acc[mt][r][s], 0, 0, 0);
          }
      }
    }
  }

  // ---- epilogue: bias + ReLU + store (C/D: col=lane&15, row=(lane>>4)*4+reg)
#pragma unroll
  for (int mt = 0; mt < 2; ++mt)
#pragma unroll
    for (int r = 0; r < 2; ++r)
#pragma unroll
      for (int s = 0; s < 2; ++s)
#pragma unroll
        for (int reg = 0; reg < 4; ++reg) {
          int co = ch * 32 + mt * 16 + lg * 4 + reg;
          if (co < CCH) {
            int px = px0g + ph * 32 + s * 16 + ln15;
            int row = row0 + r;
            float v = acc[mt][r][s][reg] + b1[co];
            x1[(((size_t)b * CCH + co) << 16) + (row << 8) + px] = fmaxf(v, 0.f);
          }
        }
}

// ---------------- Kernel 2: conv3x3 (50->2) + softmax[:,1] ----------------
__global__ __launch_bounds__(256) void conv2_softmax_k(
    const float* __restrict__ x1, const float* __restrict__ w2,
    const float* __restrict__ b2, float* __restrict__ sm) {
  int idx = blockIdx.x * 256 + threadIdx.x;
  int b = idx >> 16, hw = idx & 65535;
  int h = hw >> 8, w = hw & 255;
  const float* ip = x1 + (size_t)b * CCH * 65536 + hw;

  float a0 = b2[0], a1 = b2[1];
  bool hm = h > 0, hp = h < HH - 1, wm = w > 0, wp = w < WW - 1;

  for (int ci = 0; ci < CCH; ++ci) {
    const float* p = ip + (size_t)ci * 65536;
    float v0 = (hm && wm) ? p[-257] : 0.f;
    float v1 = hm         ? p[-256] : 0.f;
    float v2 = (hm && wp) ? p[-255] : 0.f;
    float v3 = wm         ? p[-1]   : 0.f;
    float v4 =              p[0];
    float v5 = wp         ? p[1]    : 0.f;
    float v6 = (hp && wm) ? p[255]  : 0.f;
    float v7 = hp         ? p[256]  : 0.f;
    float v8 = (hp && wp) ? p[257]  : 0.f;
    const float* q0 = w2 + ci * 9;
    const float* q1 = w2 + CCH * 9 + ci * 9;
    a0 = fmaf(q0[0], v0, a0); a0 = fmaf(q0[1], v1, a0); a0 = fmaf(q0[2], v2, a0);
    a0 = fmaf(q0[3], v3, a0); a0 = fmaf(q0[4], v4, a0); a0 = fmaf(q0[5], v5, a0);
    a0 = fmaf(q0[6], v6, a0); a0 = fmaf(q0[7], v7, a0); a0 = fmaf(q0[8], v8, a0);
    a1 = fmaf(q1[0], v0, a1); a1 = fmaf(q1[1], v1, a1); a1 = fmaf(q1[2], v2, a1);
    a1 = fmaf(q1[3], v3, a1); a1 = fmaf(q1[4], v4, a1); a1 = fmaf(q1[5], v5, a1);
    a1 = fmaf(q1[6], v6, a1); a1 = fmaf(q1[7], v7, a1); a1 = fmaf(q1[8], v8, a1);
  }
  sm[(size_t)b * 65536 + hw] = 1.f / (1.f + expf(a0 - a1));
}

// ---------------- Kernel 3: 4x4 avg pool + LeakyReLU(0.1) ----------------
__global__ __launch_bounds__(256) void pool_leaky_k(
    const float* __restrict__ sm, float* __restrict__ pool) {
  int idx = blockIdx.x * 256 + threadIdx.x;
  int b = idx >> 12, hw = idx & 4095;
  int hs = hw >> 6, ws = hw & 63;
  const float* p = sm + (size_t)b * 65536 + hs * 4 * WW + ws * 4;
  float s = 0.f;
#pragma unroll
  for (int r = 0; r < 4; ++r)
#pragma unroll
    for (int c = 0; c < 4; ++c) s += p[r * WW + c];
  s *= (1.f / 16.f);
  pool[idx] = (s >= 0.f) ? s : 0.1f * s;
}

// ---------------- Kernel 4: 25-tap learned mixing -> final_mask ----------------
__global__ __launch_bounds__(256) void mix_mask_k(
    const float* __restrict__ pool, const float* __restrict__ wk,
    const float* __restrict__ bk, float* __restrict__ mask_out) {
  int idx = blockIdx.x * 256 + threadIdx.x;
  int b = idx >> 12, hw = idx & 4095;
  int hs = hw >> 6, ws = hw & 63;
  float c = pool[idx];
  float s = 0.f;
#pragma unroll
  for (int i = 0; i < 5; ++i) {
#pragma unroll
    for (int j = 0; j < 5; ++j) {
      int y = hs + i - 2, x = ws + j - 2;
      float win = (y >= 0 && y < HSZ && x >= 0 && x < WSZ)
                      ? pool[(size_t)b * 4096 + y * WSZ + x] : 0.f;
      int k = i * 5 + j;
      s += (wk[k] * c + bk[k]) * win;
    }
  }
  mask_out[idx] = s;
}

// ---------------- Kernel 5: per-batch top-240 + ascending index sort ----------------
__global__ __launch_bounds__(256) void topk_sort_k(
    const float* __restrict__ mask, float* __restrict__ ob, float* __restrict__ oh,
    float* __restrict__ ow, int* __restrict__ idx_ws) {
  __shared__ unsigned long long keys[4096];
  __shared__ int sidx[256];
  int b = blockIdx.x, t = threadIdx.x;

  for (int i = t; i < 4096; i += 256) {
    float v = mask[(size_t)b * 4096 + i];
    unsigned u = __float_as_uint(v);
    u = (u & 0x80000000u) ? ~u : (u | 0x80000000u);
    u = ~u;
    keys[i] = ((unsigned long long)u << 12) | (unsigned)i;
  }
  __syncthreads();

  for (int k = 2; k <= 4096; k <<= 1) {
    for (int j = k >> 1; j > 0; j >>= 1) {
      for (int m = t; m < 2048; m += 256) {
        int i = ((m & ~(j - 1)) << 1) | (m & (j - 1));
        int l = i | j;
        bool up = ((i & k) == 0);
        unsigned long long a = keys[i], c = keys[l];
        if ((a > c) == up) { keys[i] = c; keys[l] = a; }
      }
      __syncthreads();
    }
  }

  sidx[t] = (t < NTOP) ? (int)(keys[t] & 0xFFFu) : 0x7FFFFFFF;
  __syncthreads();
  for (int k = 2; k <= 256; k <<= 1) {
    for (int j = k >> 1; j > 0; j >>= 1) {
      if (t < 128) {
        int i = ((t & ~(j - 1)) << 1) | (t & (j - 1));
        int l = i | j;
        bool up = ((i & k) == 0);
        int a = sidx[i], c = sidx[l];
        if ((a > c) == up) { sidx[i] = c; sidx[l] = a; }
      }
      __syncthreads();
    }
  }

  if (t < NTOP) {
    int id = sidx[t];
    int o = b * NTOP + t;
    ob[o] = (float)b;
    oh[o] = (float)(id >> 6);
    ow[o] = (float)(id & 63);
    idx_ws[o] = id;
  }
}

// ---------------- Kernel 6: gather 6x6 patches (pad=1, stride=4) ----------------
__global__ __launch_bounds__(256) void gather_patch_k(
    const float* __restrict__ in, const int* __restrict__ idx_ws,
    float* __restrict__ patches) {
  int p = blockIdx.x;
  int b = p / NTOP;
  int id = idx_ws[p];
  int h = id >> 6, w = id & 63;
  int y0 = h * 4 - 1, x0 = w * 4 - 1;
  const float* base = in + (size_t)b * CCH * 65536;
  float* op = patches + (size_t)p * (CCH * 36);
  for (int e = threadIdx.x; e < CCH * 36; e += 256) {
    int c = e / 36;
    int r = (e - c * 36) / 6;
    int col = e - c * 36 - r * 6;
    int y = y0 + r, x = x0 + col;
    float v = 0.f;
    if (y >= 0 && y < HH && x >= 0 && x < WW)
      v = base[(size_t)c * 65536 + y * WW + x];
    op[e] = v;
  }
}

extern "C" void kernel_launch(void* const* d_in, const int* in_sizes, int n_in,
                              void* d_out, int out_size, void* d_ws, size_t ws_size,
                              hipStream_t stream) {
  const float* out_lr = (const float*)d_in[0];
  const float* W1 = (const float*)d_in[1];
  const float* b1 = (const float*)d_in[2];
  const float* W2 = (const float*)d_in[3];
  const float* b2 = (const float*)d_in[4];
  const float* Wk = (const float*)d_in[5];
  const float* bk = (const float*)d_in[6];

  float* x1   = (float*)d_ws;                 // 16*50*256*256 = 52,428,800
  float* sm   = x1 + (size_t)52428800;        // 16*256*256    =  1,048,576
  float* pool = sm + (size_t)1048576;         // 16*64*64      =     65,536
  int*  idxb  = (int*)(pool + 65536);         // 16*240        =      3,840
  unsigned short* wfrag = (unsigned short*)(pool + 65536 + 3840);  // 73,728 bf16

  float* out    = (float*)d_out;
  float* o_patch = out;                        // 3840*50*36
  float* o_b    = out + (size_t)6912000;
  float* o_h    = o_b + 3840;
  float* o_w    = o_h + 3840;
  float* o_mask = o_w + 3840;                  // 16*4096

  prep_wfrag_k<<<144, 64, 0, stream>>>(W1, wfrag);
  conv1_mfma_k<<<BATCH * 128 * 4, 256, 0, stream>>>(out_lr, wfrag, b1, x1);
  conv2_softmax_k<<<4096, 256, 0, stream>>>(x1, W2, b2, sm);
  pool_leaky_k<<<256, 256, 0, stream>>>(sm, pool);
  mix_mask_k<<<256, 256, 0, stream>>>(pool, Wk, bk, o_mask);
  topk_sort_k<<<BATCH, 256, 0, stream>>>(o_mask, o_b, o_h, o_w, idxb);
  gather_patch_k<<<BATCH * NTOP, 256, 0, stream>>>(out_lr, idxb, o_patch);
}

// Round 6
// 489.545 us; speedup vs baseline: 1.8054x; 1.3007x over previous
//
#include <hip/hip_runtime.h>
#include <math.h>

#define CCH   50
#define HH    256
#define WW    256
#define BATCH 16
#define HSZ   64
#define WSZ   64
#define NTOP  240
#define NPX   130     // staged px per row (128 + 2 halo)

typedef __attribute__((ext_vector_type(8))) short s16x8;
typedef __attribute__((ext_vector_type(4))) float f32x4;

__device__ __forceinline__ unsigned short bf16rne(float x) {
  unsigned u = __float_as_uint(x);
  unsigned r = (u + 0x7FFFu + ((u >> 16) & 1u)) >> 16;
  return (unsigned short)r;
}
__device__ __forceinline__ float bf2f(unsigned short h) {
  return __uint_as_float(((unsigned)h) << 16);
}

// ---------------- Kernel 0: pack W1 into MFMA A-fragments (split bf16) ----
// combo = ((chunk*9 + tap)*4 + mt)*2 + sp ; per combo 64 lanes x 8 bf16.
// element (lane, e): co = mt*16 + (lane&15), ci = chunk*32 + (lane>>4)*8 + e.
__global__ __launch_bounds__(64) void prep_wfrag_k(
    const float* __restrict__ W1, unsigned short* __restrict__ wf) {
  int combo = blockIdx.x;            // 0..143
  int lane = threadIdx.x;
  int sp = combo & 1;
  int t2 = combo >> 1;
  int mt = t2 & 3;
  int t3 = t2 >> 2;                  // 0..17
  int tap = t3 % 9;
  int chunk = t3 / 9;
  int co = mt * 16 + (lane & 15);
  int gbase = combo * 512 + lane * 8;
#pragma unroll
  for (int e = 0; e < 8; ++e) {
    int ci = chunk * 32 + ((lane >> 4) * 8) + e;
    float w = (co < CCH && ci < CCH) ? W1[co * (CCH * 9) + ci * 9 + tap] : 0.f;
    unsigned short h = bf16rne(w);
    unsigned short v = sp ? bf16rne(w - bf2f(h)) : h;
    wf[gbase + e] = v;
  }
}

// ---------------- Kernel 1: conv3x3 (50->50) + ReLU via MFMA -------------
// Tile: 2 rows x 128 px, 4 waves; each wave: 32 px x all-64 co (A traffic
// halved vs 16px waves). LDS: [4 rows][130 px][hi32|lo32 ci shorts] with
// 16B-granule XOR swizzle (granule ^= px&7) -> staging b128 writes AND
// B-frag b128 reads both uniform-depth-8 (minimal).
__global__ __launch_bounds__(256, 2) void conv1_mfma_k(
    const float* __restrict__ in, const unsigned short* __restrict__ wf,
    const float* __restrict__ b1, float* __restrict__ x1) {
  __shared__ alignas(16) short xlds[4 * NPX * 64];   // 66,560 B

  int bx = blockIdx.x;
  int pq = bx & 1;                   // px half of 256
  int rp = (bx >> 1) & 127;          // row pair
  int b  = bx >> 8;                  // batch
  int row0 = rp * 2;
  int px0g = pq * 128;

  int t = threadIdx.x;
  int lane = t & 63;
  int wv = t >> 6;                   // wave owns px [wv*32, wv*32+32)
  int ln15 = lane & 15;
  int lg = lane >> 4;

  f32x4 acc[4][2][2];                // [mt][r][s]
#pragma unroll
  for (int mt = 0; mt < 4; ++mt)
#pragma unroll
    for (int r = 0; r < 2; ++r)
#pragma unroll
      for (int s = 0; s < 2; ++s) acc[mt][r][s] = (f32x4){0.f, 0.f, 0.f, 0.f};

  const size_t in_b = ((size_t)b * CCH) << 16;
  const int pb0 = 1 + wv * 32 + ln15;          // s=0, dw=0 staged-px base

#pragma unroll
  for (int chunk = 0; chunk < 2; ++chunk) {
    __syncthreads();                 // previous chunk's reads complete
    // ---- stage: item = (row, oct, px); lane loads 8 ci for one px ----
    for (int i = t; i < 4 * 4 * NPX; i += 256) {
      int ro = i / NPX;              // row*4 + oct
      int px = i - ro * NPX;
      int row = ro >> 2, oct = ro & 3;
      int gr = row0 - 1 + row;
      int gx = px0g - 1 + px;
      bool okxy = (gr >= 0 && gr < HH && gx >= 0 && gx < WW);
      const float* gp = in + in_b + ((size_t)(chunk * 32 + oct * 8) << 16)
                        + (gr << 8) + gx;
      unsigned hs[8], ls[8];
#pragma unroll
      for (int e = 0; e < 8; ++e) {
        int ci = chunk * 32 + oct * 8 + e;
        float x = (okxy && ci < CCH) ? gp[(size_t)e << 16] : 0.f;
        unsigned u = __float_as_uint(x);
        unsigned hu = u & 0xFFFF0000u;          // trunc-split hi
        float lo = x - __uint_as_float(hu);     // exact residual
        unsigned ul = __float_as_uint(lo);
        hs[e] = hu >> 16;
        ls[e] = (ul + 0x7FFFu + ((ul >> 16) & 1u)) >> 16;   // rne lo
      }
      s16x8 hv, lv;
#pragma unroll
      for (int e = 0; e < 8; ++e) { hv[e] = (short)hs[e]; lv[e] = (short)ls[e]; }
      int swz = (px & 7) << 3;                  // 16B-granule XOR (8 shorts)
      int base_sh = (row * NPX + px) * 64;
      *(s16x8*)&xlds[base_sh + ((oct * 8) ^ swz)] = hv;
      *(s16x8*)&xlds[base_sh + ((32 + oct * 8) ^ swz)] = lv;
    }
    __syncthreads();

    // ---- 9 taps ----
#pragma unroll
    for (int tap = 0; tap < 9; ++tap) {
      const int dh = tap / 3 - 1;
      const int dw = tap % 3 - 1;
      // A fragments (all 4 co-tiles, hi+lo) — L2-hot global, 1KB/read
      s16x8 ah[4], al[4];
#pragma unroll
      for (int mt = 0; mt < 4; ++mt) {
        int cb = ((chunk * 9 + tap) * 4 + mt) * 2;
        ah[mt] = *(const s16x8*)(wf + (size_t)cb * 512 + lane * 8);
        al[mt] = *(const s16x8*)(wf + (size_t)(cb + 1) * 512 + lane * 8);
      }
#pragma unroll
      for (int r = 0; r < 2; ++r) {
#pragma unroll
        for (int s = 0; s < 2; ++s) {
          int pixL = pb0 + s * 16 + dw;
          int bsh = ((r + 1 + dh) * NPX + pixL) * 64;
          int swz = (pixL & 7) << 3;
          s16x8 bh = *(const s16x8*)&xlds[bsh + ((lg * 8) ^ swz)];
          s16x8 bl = *(const s16x8*)&xlds[bsh + ((32 + lg * 8) ^ swz)];
#pragma unroll
          for (int mt = 0; mt < 4; ++mt) {
            acc[mt][r][s] = __builtin_amdgcn_mfma_f32_16x16x32_bf16(
                ah[mt], bh, acc[mt][r][s], 0, 0, 0);
            acc[mt][r][s] = __builtin_amdgcn_mfma_f32_16x16x32_bf16(
                ah[mt], bl, acc[mt][r][s], 0, 0, 0);
            acc[mt][r][s] = __builtin_amdgcn_mfma_f32_16x16x32_bf16(
                al[mt], bh, acc[mt][r][s], 0, 0, 0);
          }
        }
      }
    }
  }

  // ---- epilogue: bias + ReLU + store (C/D: col=lane&15, row=(lane>>4)*4+reg)
#pragma unroll
  for (int mt = 0; mt < 4; ++mt)
#pragma unroll
    for (int r = 0; r < 2; ++r)
#pragma unroll
      for (int s = 0; s < 2; ++s)
#pragma unroll
        for (int reg = 0; reg < 4; ++reg) {
          int co = mt * 16 + lg * 4 + reg;
          if (co < CCH) {
            int px = px0g + wv * 32 + s * 16 + ln15;
            int row = row0 + r;
            float v = acc[mt][r][s][reg] + b1[co];
            x1[(((size_t)b * CCH + co) << 16) + (row << 8) + px] = fmaxf(v, 0.f);
          }
        }
}

// ---------------- Kernel 2: conv3x3 (50->2) + softmax[:,1] ----------------
__global__ __launch_bounds__(256) void conv2_softmax_k(
    const float* __restrict__ x1, const float* __restrict__ w2,
    const float* __restrict__ b2, float* __restrict__ sm) {
  int idx = blockIdx.x * 256 + threadIdx.x;
  int b = idx >> 16, hw = idx & 65535;
  int h = hw >> 8, w = hw & 255;
  const float* ip = x1 + (size_t)b * CCH * 65536 + hw;

  float a0 = b2[0], a1 = b2[1];
  bool hm = h > 0, hp = h < HH - 1, wm = w > 0, wp = w < WW - 1;

  for (int ci = 0; ci < CCH; ++ci) {
    const float* p = ip + (size_t)ci * 65536;
    float v0 = (hm && wm) ? p[-257] : 0.f;
    float v1 = hm         ? p[-256] : 0.f;
    float v2 = (hm && wp) ? p[-255] : 0.f;
    float v3 = wm         ? p[-1]   : 0.f;
    float v4 =              p[0];
    float v5 = wp         ? p[1]    : 0.f;
    float v6 = (hp && wm) ? p[255]  : 0.f;
    float v7 = hp         ? p[256]  : 0.f;
    float v8 = (hp && wp) ? p[257]  : 0.f;
    const float* q0 = w2 + ci * 9;
    const float* q1 = w2 + CCH * 9 + ci * 9;
    a0 = fmaf(q0[0], v0, a0); a0 = fmaf(q0[1], v1, a0); a0 = fmaf(q0[2], v2, a0);
    a0 = fmaf(q0[3], v3, a0); a0 = fmaf(q0[4], v4, a0); a0 = fmaf(q0[5], v5, a0);
    a0 = fmaf(q0[6], v6, a0); a0 = fmaf(q0[7], v7, a0); a0 = fmaf(q0[8], v8, a0);
    a1 = fmaf(q1[0], v0, a1); a1 = fmaf(q1[1], v1, a1); a1 = fmaf(q1[2], v2, a1);
    a1 = fmaf(q1[3], v3, a1); a1 = fmaf(q1[4], v4, a1); a1 = fmaf(q1[5], v5, a1);
    a1 = fmaf(q1[6], v6, a1); a1 = fmaf(q1[7], v7, a1); a1 = fmaf(q1[8], v8, a1);
  }
  sm[(size_t)b * 65536 + hw] = 1.f / (1.f + expf(a0 - a1));
}

// ---------------- Kernel 3: 4x4 avg pool + LeakyReLU(0.1) ----------------
__global__ __launch_bounds__(256) void pool_leaky_k(
    const float* __restrict__ sm, float* __restrict__ pool) {
  int idx = blockIdx.x * 256 + threadIdx.x;
  int b = idx >> 12, hw = idx & 4095;
  int hs = hw >> 6, ws = hw & 63;
  const float* p = sm + (size_t)b * 65536 + hs * 4 * WW + ws * 4;
  float s = 0.f;
#pragma unroll
  for (int r = 0; r < 4; ++r)
#pragma unroll
    for (int c = 0; c < 4; ++c) s += p[r * WW + c];
  s *= (1.f / 16.f);
  pool[idx] = (s >= 0.f) ? s : 0.1f * s;
}

// ---------------- Kernel 4: 25-tap learned mixing -> final_mask ----------------
__global__ __launch_bounds__(256) void mix_mask_k(
    const float* __restrict__ pool, const float* __restrict__ wk,
    const float* __restrict__ bk, float* __restrict__ mask_out) {
  int idx = blockIdx.x * 256 + threadIdx.x;
  int b = idx >> 12, hw = idx & 4095;
  int hs = hw >> 6, ws = hw & 63;
  float c = pool[idx];
  float s = 0.f;
#pragma unroll
  for (int i = 0; i < 5; ++i) {
#pragma unroll
    for (int j = 0; j < 5; ++j) {
      int y = hs + i - 2, x = ws + j - 2;
      float win = (y >= 0 && y < HSZ && x >= 0 && x < WSZ)
                      ? pool[(size_t)b * 4096 + y * WSZ + x] : 0.f;
      int k = i * 5 + j;
      s += (wk[k] * c + bk[k]) * win;
    }
  }
  mask_out[idx] = s;
}

// ---------------- Kernel 5: per-batch top-240 + ascending index sort ----------------
__global__ __launch_bounds__(256) void topk_sort_k(
    const float* __restrict__ mask, float* __restrict__ ob, float* __restrict__ oh,
    float* __restrict__ ow, int* __restrict__ idx_ws) {
  __shared__ unsigned long long keys[4096];
  __shared__ int sidx[256];
  int b = blockIdx.x, t = threadIdx.x;

  for (int i = t; i < 4096; i += 256) {
    float v = mask[(size_t)b * 4096 + i];
    unsigned u = __float_as_uint(v);
    u = (u & 0x80000000u) ? ~u : (u | 0x80000000u);
    u = ~u;
    keys[i] = ((unsigned long long)u << 12) | (unsigned)i;
  }
  __syncthreads();

  for (int k = 2; k <= 4096; k <<= 1) {
    for (int j = k >> 1; j > 0; j >>= 1) {
      for (int m = t; m < 2048; m += 256) {
        int i = ((m & ~(j - 1)) << 1) | (m & (j - 1));
        int l = i | j;
        bool up = ((i & k) == 0);
        unsigned long long a = keys[i], c = keys[l];
        if ((a > c) == up) { keys[i] = c; keys[l] = a; }
      }
      __syncthreads();
    }
  }

  sidx[t] = (t < NTOP) ? (int)(keys[t] & 0xFFFu) : 0x7FFFFFFF;
  __syncthreads();
  for (int k = 2; k <= 256; k <<= 1) {
    for (int j = k >> 1; j > 0; j >>= 1) {
      if (t < 128) {
        int i = ((t & ~(j - 1)) << 1) | (t & (j - 1));
        int l = i | j;
        bool up = ((i & k) == 0);
        int a = sidx[i], c = sidx[l];
        if ((a > c) == up) { sidx[i] = c; sidx[l] = a; }
      }
      __syncthreads();
    }
  }

  if (t < NTOP) {
    int id = sidx[t];
    int o = b * NTOP + t;
    ob[o] = (float)b;
    oh[o] = (float)(id >> 6);
    ow[o] = (float)(id & 63);
    idx_ws[o] = id;
  }
}

// ---------------- Kernel 6: gather 6x6 patches (pad=1, stride=4) ----------------
__global__ __launch_bounds__(256) void gather_patch_k(
    const float* __restrict__ in, const int* __restrict__ idx_ws,
    float* __restrict__ patches) {
  int p = blockIdx.x;
  int b = p / NTOP;
  int id = idx_ws[p];
  int h = id >> 6, w = id & 63;
  int y0 = h * 4 - 1, x0 = w * 4 - 1;
  const float* base = in + (size_t)b * CCH * 65536;
  float* op = patches + (size_t)p * (CCH * 36);
  for (int e = threadIdx.x; e < CCH * 36; e += 256) {
    int c = e / 36;
    int r = (e - c * 36) / 6;
    int col = e - c * 36 - r * 6;
    int y = y0 + r, x = x0 + col;
    float v = 0.f;
    if (y >= 0 && y < HH && x >= 0 && x < WW)
      v = base[(size_t)c * 65536 + y * WW + x];
    op[e] = v;
  }
}

extern "C" void kernel_launch(void* const* d_in, const int* in_sizes, int n_in,
                              void* d_out, int out_size, void* d_ws, size_t ws_size,
                              hipStream_t stream) {
  const float* out_lr = (const float*)d_in[0];
  const float* W1 = (const float*)d_in[1];
  const float* b1 = (const float*)d_in[2];
  const float* W2 = (const float*)d_in[3];
  const float* b2 = (const float*)d_in[4];
  const float* Wk = (const float*)d_in[5];
  const float* bk = (const float*)d_in[6];

  float* x1   = (float*)d_ws;                 // 16*50*256*256 = 52,428,800
  float* sm   = x1 + (size_t)52428800;        // 16*256*256    =  1,048,576
  float* pool = sm + (size_t)1048576;         // 16*64*64      =     65,536
  int*  idxb  = (int*)(pool + 65536);         // 16*240        =      3,840
  unsigned short* wfrag = (unsigned short*)(pool + 65536 + 3840);  // 73,728 bf16

  float* out    = (float*)d_out;
  float* o_patch = out;                        // 3840*50*36
  float* o_b    = out + (size_t)6912000;
  float* o_h    = o_b + 3840;
  float* o_w    = o_h + 3840;
  float* o_mask = o_w + 3840;                  // 16*4096

  prep_wfrag_k<<<144, 64, 0, stream>>>(W1, wfrag);
  conv1_mfma_k<<<BATCH * 128 * 2, 256, 0, stream>>>(out_lr, wfrag, b1, x1);
  conv2_softmax_k<<<4096, 256, 0, stream>>>(x1, W2, b2, sm);
  pool_leaky_k<<<256, 256, 0, stream>>>(sm, pool);
  mix_mask_k<<<256, 256, 0, stream>>>(pool, Wk, bk, o_mask);
  topk_sort_k<<<BATCH, 256, 0, stream>>>(o_mask, o_b, o_h, o_w, idxb);
  gather_patch_k<<<BATCH * NTOP, 256, 0, stream>>>(out_lr, idxb, o_patch);
}